// Round 19
// baseline (132.719 us; speedup 1.0000x reference)
//
#include <hip/hip_runtime.h>
#include <math.h>

#define BATCH 16
#define CCH 256
#define LSEQ 4096
#define NB 4
#define CB 64
#define MA_H 12
#define BN_EPS 1e-5f

typedef __attribute__((ext_vector_type(8))) short bf16x8;
typedef __attribute__((ext_vector_type(4))) float f32x4;

__device__ inline float b2f(ushort u) {
    union { uint i; float f; } v; v.i = ((uint)u) << 16; return v.f;
}
__device__ inline ushort f2b(float f) {   // round-to-nearest-even
    uint x = __float_as_uint(f);
    return (ushort)((x + 0x7FFFu + ((x >> 16) & 1u)) >> 16);
}
// branch-free tanh-form GELU (max |err| vs exact-erf GELU ~3e-4, << bf16 quantum)
__device__ inline float gelu_fast(float v) {
    float t2 = fmaf(0.044715f, v * v, 1.f);
    float u2 = 1.59576912160573f * v * t2;     // 2*sqrt(2/pi)*(v+0.044715v^3)
    float e  = __expf(u2);
    float r  = __frcp_rn(e + 1.f);
    return v * (1.f - r);                       // = 0.5v(1+tanh(u))
}

// ---------------------------------------------------------------------------
// Kernel 0w: fold the branch cumsum into the fusion weights.
// ---------------------------------------------------------------------------
__global__ __launch_bounds__(256) void k0w_fusionw(const float* __restrict__ fw,
                                                   ushort* __restrict__ wbf2)
{
    int e = blockIdx.x * 256 + threadIdx.x;   // 256*64 = 16384
    int o = e >> 6, j = e & 63;
    const float* row = fw + (size_t)o * 512;
    float ws0 = row[j],       ws1 = row[64 + j],
          ws2 = row[128 + j], ws3 = row[192 + j];
    float wl0 = row[256 + j], wl1 = row[320 + j],
          wl2 = row[384 + j], wl3 = row[448 + j];
    float S3 = ws3, S2 = ws2 + S3, S1 = ws1 + S2, S0 = ws0 + S1;
    float L0 = wl0, L1 = L0 + wl1, L2 = L1 + wl2, L3 = L2 + wl3;
    ushort* dst = wbf2 + (size_t)o * 512;
    dst[j]        = f2b(S0); dst[64 + j]  = f2b(S1);
    dst[128 + j]  = f2b(S2); dst[192 + j] = f2b(S3);
    dst[256 + j]  = f2b(L0 - S0); dst[320 + j] = f2b(L1 - S1);
    dst[384 + j]  = f2b(L2 - S2); dst[448 + j] = f2b(L3 - S3);
}

// ---------------------------------------------------------------------------
// Kernel 0b: reorder branch conv weights -> wbr[br][o][kk*64+i] bf16
// ---------------------------------------------------------------------------
__global__ __launch_bounds__(256) void k0b_convw_branch(
    const float* __restrict__ conv_w, ushort* __restrict__ wbr)
{
    int e = blockIdx.x * 256 + threadIdx.x;     // 49152
    int i    = e & 63;
    int rest = e >> 6;
    int kk   = rest % 3;
    int orow = rest / 3;
    float v = conv_w[(size_t)orow * 192 + i * 3 + kk];
    wbr[(size_t)orow * 192 + kk * 64 + i] = f2b(v);
}

// ---------------------------------------------------------------------------
// Kernel 0c: transpose x [B][C][L] fp32 -> xT [B][L][C] bf16
// ---------------------------------------------------------------------------
__global__ __launch_bounds__(256) void k0c_xT(const float* __restrict__ x,
                                              ushort* __restrict__ xT)
{
    const int p0    = blockIdx.x * 64;
    const int batch = blockIdx.y;
    const int tid   = threadIdx.x;

    __shared__ uint ls[256 * 33];

    const float* xb = x + (size_t)batch * CCH * LSEQ;
#pragma unroll
    for (int pass = 0; pass < 16; ++pass) {
        int e  = tid + pass * 256;
        int ch = e >> 4;
        int c4 = e & 15;
        float4 v = *(const float4*)&xb[(size_t)ch * LSEQ + p0 + c4 * 4];
        uint u0 = (uint)f2b(v.x) | ((uint)f2b(v.y) << 16);
        uint u1 = (uint)f2b(v.z) | ((uint)f2b(v.w) << 16);
        ls[ch * 33 + c4 * 2]     = u0;
        ls[ch * 33 + c4 * 2 + 1] = u1;
    }
    __syncthreads();

    const int w = tid >> 6, l = tid & 63;
    const ushort* lsu = (const ushort*)ls;
    ushort* dst = xT + ((size_t)batch * LSEQ + p0) * CCH;
#pragma unroll
    for (int r = 0; r < 16; ++r) {
        int p = w * 16 + r;
#pragma unroll
        for (int q = 0; q < 4; ++q) {
            int ch = l + 64 * q;
            dst[(size_t)p * CCH + ch] = lsu[ch * 66 + p];
        }
    }
}

// ---------------------------------------------------------------------------
// Kernel 1: dilated conv(k=3) MFMA GEMM + BN + fast GELU, multi-tile.
// K1T=2, grid (16, 4 branches, 16 batch) -> 1024 blocks = 4/CU
// ---------------------------------------------------------------------------
#define SXA 72
#define SWB 200
#define K1T 2
__global__ __launch_bounds__(256) void k1_conv_mfma(
    const ushort* __restrict__ xT, const ushort* __restrict__ wbr,
    const float* __restrict__ conv_b, const float* __restrict__ bn_gamma,
    const float* __restrict__ bn_beta, const float* __restrict__ bn_mean,
    const float* __restrict__ bn_var, ushort* __restrict__ hT)
{
    const int br    = blockIdx.y;
    const int batch = blockIdx.z;
    const int d     = 1 << br;
    const int tid   = threadIdx.x;
    const int wm    = tid >> 6;
    const int lane  = tid & 63;
    const int lo    = lane & 15;
    const int hi    = lane >> 4;

    __shared__ ushort xsA[144 * SXA];   // A tile / reused as output transpose
    __shared__ ushort wlB[64 * SWB];

    const ushort* xTb = xT + (size_t)batch * LSEQ * CCH + br * CB;

    // ---- stage B once ----
    {
        const ushort* wrow = wbr + ((size_t)br * CB) * 192;
#pragma unroll
        for (int pass = 0; pass < 6; ++pass) {
            int e = tid + pass * 256;
            int o = e / 24;
            int c = e - o * 24;
            uint4 v = *(const uint4*)&wrow[e * 8];
            *(uint4*)&wlB[o * SWB + c * 8] = v;
        }
    }
    // ---- hoist BN params (loop-invariant) ----
    float bias[4], sc[4], sh[4];
#pragma unroll
    for (int ni = 0; ni < 4; ++ni) {
        const int go = br * CB + ni * 16 + lo;
        bias[ni] = conv_b[go];
        float inv = rsqrtf(bn_var[go] + BN_EPS);
        sc[ni] = bn_gamma[go] * inv;
        sh[ni] = bn_beta[go] - bn_mean[go] * sc[ni];
    }

    const int arow = tid >> 3;
    const int acol = tid & 7;
    uint4 areg[5];
    {
        const int t0 = blockIdx.x * (K1T * 128);
#pragma unroll
        for (int pass = 0; pass < 5; ++pass) {
            int p = arow + pass * 32;
            areg[pass] = make_uint4(0u, 0u, 0u, 0u);
            if (p < 144) {
                int gp = t0 - 8 + p;
                if (gp >= 0 && gp < LSEQ)
                    areg[pass] = *(const uint4*)&xTb[(size_t)gp * CCH + acol * 8];
            }
        }
    }

    for (int t = 0; t < K1T; ++t) {
        const int t0 = blockIdx.x * (K1T * 128) + t * 128;
        __syncthreads();
#pragma unroll
        for (int pass = 0; pass < 5; ++pass) {
            int p = arow + pass * 32;
            if (p < 144) *(uint4*)&xsA[p * SXA + acol * 8] = areg[pass];
        }
        __syncthreads();

        f32x4 acc[2][4];
#pragma unroll
        for (int mi = 0; mi < 2; ++mi)
#pragma unroll
            for (int ni = 0; ni < 4; ++ni) acc[mi][ni] = (f32x4)0.f;

#pragma unroll
        for (int kk = 0; kk < 3; ++kk) {
            const int roff = 8 + (kk - 1) * d;
#pragma unroll
            for (int ks = 0; ks < 2; ++ks) {
                bf16x8 af[2], bfr[4];
#pragma unroll
                for (int mi = 0; mi < 2; ++mi)
                    af[mi] = *(const bf16x8*)&xsA[
                        (wm * 32 + mi * 16 + lo + roff) * SXA + ks * 32 + hi * 8];
#pragma unroll
                for (int ni = 0; ni < 4; ++ni)
                    bfr[ni] = *(const bf16x8*)&wlB[
                        (ni * 16 + lo) * SWB + kk * 64 + ks * 32 + hi * 8];
#pragma unroll
                for (int mi = 0; mi < 2; ++mi)
#pragma unroll
                    for (int ni = 0; ni < 4; ++ni)
                        acc[mi][ni] = __builtin_amdgcn_mfma_f32_16x16x32_bf16(
                            af[mi], bfr[ni], acc[mi][ni], 0, 0, 0);
            }
        }

        // ---- issue next tile's A loads (latency hides under epilogue) ----
        if (t + 1 < K1T) {
            const int tn = t0 + 128;
#pragma unroll
            for (int pass = 0; pass < 5; ++pass) {
                int p = arow + pass * 32;
                areg[pass] = make_uint4(0u, 0u, 0u, 0u);
                if (p < 144) {
                    int gp = tn - 8 + p;
                    if (gp >= 0 && gp < LSEQ)
                        areg[pass] = *(const uint4*)&xTb[(size_t)gp * CCH + acol * 8];
                }
            }
        }

        __syncthreads();
        ushort* os = xsA;                // reuse as [128 pos][64 ch]
#pragma unroll
        for (int ni = 0; ni < 4; ++ni) {
            const int o = ni * 16 + lo;
#pragma unroll
            for (int mi = 0; mi < 2; ++mi) {
                const int prow = wm * 32 + mi * 16 + hi * 4;
#pragma unroll
                for (int q = 0; q < 4; ++q) {
                    float v = acc[mi][ni][q] + bias[ni];
                    v = v * sc[ni] + sh[ni];
                    os[(prow + q) * SXA + o] = f2b(gelu_fast(v));
                }
            }
        }
        __syncthreads();
        ushort* hTb = hT + ((size_t)batch * LSEQ + t0) * CCH + br * CB;
#pragma unroll
        for (int pass = 0; pass < 4; ++pass) {
            int e = tid + pass * 256;
            int r = e >> 3;
            int c = e & 7;
            *(uint4*)&hTb[(size_t)r * CCH + c * 8] = *(const uint4*)&xsA[r * SXA + c * 8];
        }
    }
}

// ---------------------------------------------------------------------------
// Kernel 3 (fused): out = ReLU( hT·WS + MA(hT·WL) + fb ) + alpha*x
// MA commutes with the 1x1 conv.  o-tile = 64 so G (192 pos x 64 o = 48
// 16x16 tiles) is FULLY covered by 4 waves x accG[3][4]  (round-18 bug:
// 128-o tile needed 96 tiles but only 48 were computed).
// Per block: S = A[32..159]·WS (accS[2][4], wave = 32-row strip),
//            G = A[0..191]·WL  (accG[3][4], wave = 48-row strip).
// G -> G_l[64 o][196] bf16 -> 25-tap running-sum MA -> M_l[64 o][132]
// (separate buffer, no in-place hazard) -> epilogue ReLU(S+M+b) + alpha*x.
// grid (32 posTiles, 4 oTiles, 16 batch), block 256
// ---------------------------------------------------------------------------
__global__ __launch_bounds__(256) void k3_fused(
    const ushort* __restrict__ hT, const ushort* __restrict__ wbf2,
    const float* __restrict__ fb, const float* __restrict__ x,
    const float* __restrict__ alpha, float* __restrict__ out)
{
    const int t0    = blockIdx.x * 128;
    const int oBase = blockIdx.y * 64;
    const int batch = blockIdx.z;
    const int tid   = threadIdx.x;
    const int wid   = tid >> 6;
    const int lane  = tid & 63;
    const int lo    = lane & 15;
    const int hi    = lane >> 4;

    // A[192*72]=13824 | WS[64*72]=4608 | WL[64*72]=4608  -> 23040 ushorts
    // after main loop: G_l[64*196]=12544 @0 ; M_l[64*132]=8448 @13824
    __shared__ __align__(16) ushort SMEM[23040];
    ushort* A_s  = SMEM;                 // stride 72
    ushort* WS_s = SMEM + 13824;         // stride 72
    ushort* WL_s = SMEM + 18432;         // stride 72
    ushort* G_l  = SMEM;                 // [o][196]
    ushort* M_l  = SMEM + 13824;         // [o][132]

    f32x4 accS[2][4];
    f32x4 accG[3][4];
#pragma unroll
    for (int a = 0; a < 2; ++a)
#pragma unroll
        for (int b = 0; b < 4; ++b) accS[a][b] = (f32x4)0.f;
#pragma unroll
    for (int a = 0; a < 3; ++a)
#pragma unroll
        for (int b = 0; b < 4; ++b) accG[a][b] = (f32x4)0.f;

    const ushort* hTb = hT + ((size_t)batch * LSEQ) * CCH;

    for (int kn = 0; kn < 4; ++kn) {     // K-steps of 64 ch (K=256)
        __syncthreads();                 // previous MFMA reads done
        // ---- stage A: 192 rows (pos t0-32..t0+159, edge-clamped) ----
#pragma unroll
        for (int pass = 0; pass < 6; ++pass) {
            int e = tid + pass * 256;    // 192*8 = 1536
            int r = e >> 3;
            int c = e & 7;
            int gp = t0 - 32 + r;
            gp = max(0, min(LSEQ - 1, gp));
            *(uint4*)&A_s[r * 72 + c * 8] =
                *(const uint4*)&hTb[(size_t)gp * CCH + kn * 64 + c * 8];
        }
        // ---- stage WS / WL: 64 rows each ----
#pragma unroll
        for (int pass = 0; pass < 2; ++pass) {
            int e = tid + pass * 256;    // 64*8 = 512
            int r = e >> 3;
            int c = e & 7;
            const ushort* wrow = wbf2 + (size_t)(oBase + r) * 512;
            *(uint4*)&WS_s[r * 72 + c * 8] = *(const uint4*)&wrow[kn * 64 + c * 8];
            *(uint4*)&WL_s[r * 72 + c * 8] = *(const uint4*)&wrow[256 + kn * 64 + c * 8];
        }
        __syncthreads();

#pragma unroll
        for (int ks = 0; ks < 2; ++ks) {
            bf16x8 afS[2], afG[3], bS[4], bL[4];
#pragma unroll
            for (int mi = 0; mi < 2; ++mi)
                afS[mi] = *(const bf16x8*)&A_s[
                    (32 + wid * 32 + mi * 16 + lo) * 72 + ks * 32 + hi * 8];
#pragma unroll
            for (int j = 0; j < 3; ++j)
                afG[j] = *(const bf16x8*)&A_s[
                    (wid * 48 + j * 16 + lo) * 72 + ks * 32 + hi * 8];
#pragma unroll
            for (int ni = 0; ni < 4; ++ni) {
                bS[ni] = *(const bf16x8*)&WS_s[
                    (ni * 16 + lo) * 72 + ks * 32 + hi * 8];
                bL[ni] = *(const bf16x8*)&WL_s[
                    (ni * 16 + lo) * 72 + ks * 32 + hi * 8];
            }
#pragma unroll
            for (int mi = 0; mi < 2; ++mi)
#pragma unroll
                for (int ni = 0; ni < 4; ++ni)
                    accS[mi][ni] = __builtin_amdgcn_mfma_f32_16x16x32_bf16(
                        afS[mi], bS[ni], accS[mi][ni], 0, 0, 0);
#pragma unroll
            for (int j = 0; j < 3; ++j)
#pragma unroll
                for (int ni = 0; ni < 4; ++ni)
                    accG[j][ni] = __builtin_amdgcn_mfma_f32_16x16x32_bf16(
                        afG[j], bL[ni], accG[j][ni], 0, 0, 0);
        }
    }
    __syncthreads();                     // main-loop LDS reads complete

    // ---- dump G (bf16) into G_l[o][grow]; full coverage: wave strip 48 ----
#pragma unroll
    for (int j = 0; j < 3; ++j)
#pragma unroll
        for (int ni = 0; ni < 4; ++ni) {
            int o    = ni * 16 + lo;
            int grow = wid * 48 + j * 16 + hi * 4;
            ushort4 gv;
            gv.x = f2b(accG[j][ni][0]); gv.y = f2b(accG[j][ni][1]);
            gv.z = f2b(accG[j][ni][2]); gv.w = f2b(accG[j][ni][3]);
            *(ushort4*)&G_l[o * 196 + grow] = gv;
        }
    __syncthreads();

    // ---- 25-tap MA: out p = mean(G rows p+20..p+44); 64 o x 4 chunks ----
    {
        const int o  = tid & 63;
        const int p0 = (tid >> 6) * 32;
        const int ob = o * 196;
        const float inv25 = 1.f / 25.f;
        float s = 0.f;
#pragma unroll
        for (int r = 20; r <= 44; ++r) s += b2f(G_l[ob + p0 + r]);
        M_l[o * 132 + p0] = f2b(s * inv25);
#pragma unroll 4
        for (int t = 1; t < 32; ++t) {
            s += b2f(G_l[ob + p0 + t + 44]) - b2f(G_l[ob + p0 + t + 19]);
            M_l[o * 132 + p0 + t] = f2b(s * inv25);
        }
    }
    __syncthreads();

    // ---- epilogue: ReLU(S + M + bias) + alpha*x ----
    const float al = alpha[0];
#pragma unroll
    for (int ni = 0; ni < 4; ++ni) {
        const int ol = ni * 16 + lo;
        const int o  = oBase + ol;
        const float bias = fb[o];
#pragma unroll
        for (int mi = 0; mi < 2; ++mi) {
            const int pl  = wid * 32 + mi * 16 + hi * 4;
            const int pos = t0 + pl;
            ushort4 m4 = *(const ushort4*)&M_l[ol * 132 + pl];
            size_t base = ((size_t)(batch * CCH + o)) * LSEQ + pos;
            float4 xv = *(const float4*)&x[base];
            float4 ov;
            ov.x = fmaxf(accS[mi][ni][0] + b2f(m4.x) + bias, 0.f) + al * xv.x;
            ov.y = fmaxf(accS[mi][ni][1] + b2f(m4.y) + bias, 0.f) + al * xv.y;
            ov.z = fmaxf(accS[mi][ni][2] + b2f(m4.z) + bias, 0.f) + al * xv.z;
            ov.w = fmaxf(accS[mi][ni][3] + b2f(m4.w) + bias, 0.f) + al * xv.w;
            *(float4*)&out[base] = ov;
        }
    }
}

// ---------------------------------------------------------------------------
extern "C" void kernel_launch(void* const* d_in, const int* in_sizes, int n_in,
                              void* d_out, int out_size, void* d_ws, size_t ws_size,
                              hipStream_t stream)
{
    const float* x        = (const float*)d_in[0];
    const float* conv_w   = (const float*)d_in[1];
    const float* conv_b   = (const float*)d_in[2];
    const float* bn_gamma = (const float*)d_in[3];
    const float* bn_beta  = (const float*)d_in[4];
    const float* bn_mean  = (const float*)d_in[5];
    const float* bn_var   = (const float*)d_in[6];
    const float* fw       = (const float*)d_in[7];
    const float* fb       = (const float*)d_in[8];
    const float* alpha    = (const float*)d_in[9];
    float* out = (float*)d_out;

    ushort* hT    = (ushort*)d_ws;                                      // 32 MiB
    ushort* wbf2  = (ushort*)((char*)d_ws + (size_t)96 * 1024 * 1024);  // 256 KiB
    ushort* wbr   = (ushort*)((char*)d_ws + (size_t)97 * 1024 * 1024);  // 96 KiB
    ushort* xT    = (ushort*)((char*)d_ws + (size_t)98 * 1024 * 1024);  // 32 MiB

    k0w_fusionw<<<dim3(64), 256, 0, stream>>>(fw, wbf2);
    k0b_convw_branch<<<dim3(192), 256, 0, stream>>>(conv_w, wbr);
    k0c_xT<<<dim3(64, 16), 256, 0, stream>>>(x, xT);

    dim3 g1(16, NB, BATCH);
    k1_conv_mfma<<<g1, 256, 0, stream>>>(xT, wbr, conv_b, bn_gamma, bn_beta,
                                         bn_mean, bn_var, hT);

    dim3 g3(32, 4, BATCH);
    k3_fused<<<g3, 256, 0, stream>>>(hT, wbf2, fb, x, alpha, out);
}

// Round 20
// 97.213 us; speedup vs baseline: 1.3652x; 1.3652x over previous
//
#include <hip/hip_runtime.h>
#include <math.h>

#define BATCH 16
#define CCH 256
#define LSEQ 4096
#define NB 4
#define CB 64
#define MA_H 12
#define BN_EPS 1e-5f

typedef __attribute__((ext_vector_type(8))) short bf16x8;
typedef __attribute__((ext_vector_type(4))) float f32x4;

__device__ inline float b2f(ushort u) {
    union { uint i; float f; } v; v.i = ((uint)u) << 16; return v.f;
}
__device__ inline ushort f2b(float f) {   // round-to-nearest-even
    uint x = __float_as_uint(f);
    return (ushort)((x + 0x7FFFu + ((x >> 16) & 1u)) >> 16);
}
// branch-free tanh-form GELU (max |err| vs exact-erf GELU ~3e-4, << bf16 quantum)
__device__ inline float gelu_fast(float v) {
    float t2 = fmaf(0.044715f, v * v, 1.f);
    float u2 = 1.59576912160573f * v * t2;     // 2*sqrt(2/pi)*(v+0.044715v^3)
    float e  = __expf(u2);
    float r  = __frcp_rn(e + 1.f);
    return v * (1.f - r);                       // = 0.5v(1+tanh(u))
}
// async global->LDS, 16B per lane; LDS dest = wave-uniform base + lane*16
__device__ __forceinline__ void gload_lds16(const void* g, void* l) {
    __builtin_amdgcn_global_load_lds(
        (const __attribute__((address_space(1))) void*)g,
        (__attribute__((address_space(3))) void*)l, 16, 0, 0);
}

// ---------------------------------------------------------------------------
// Kernel 0w: fold the branch cumsum into the fusion weights.
// ---------------------------------------------------------------------------
__global__ __launch_bounds__(256) void k0w_fusionw(const float* __restrict__ fw,
                                                   ushort* __restrict__ wbf2)
{
    int e = blockIdx.x * 256 + threadIdx.x;   // 256*64 = 16384
    int o = e >> 6, j = e & 63;
    const float* row = fw + (size_t)o * 512;
    float ws0 = row[j],       ws1 = row[64 + j],
          ws2 = row[128 + j], ws3 = row[192 + j];
    float wl0 = row[256 + j], wl1 = row[320 + j],
          wl2 = row[384 + j], wl3 = row[448 + j];
    float S3 = ws3, S2 = ws2 + S3, S1 = ws1 + S2, S0 = ws0 + S1;
    float L0 = wl0, L1 = L0 + wl1, L2 = L1 + wl2, L3 = L2 + wl3;
    ushort* dst = wbf2 + (size_t)o * 512;
    dst[j]        = f2b(S0); dst[64 + j]  = f2b(S1);
    dst[128 + j]  = f2b(S2); dst[192 + j] = f2b(S3);
    dst[256 + j]  = f2b(L0 - S0); dst[320 + j] = f2b(L1 - S1);
    dst[384 + j]  = f2b(L2 - S2); dst[448 + j] = f2b(L3 - S3);
}

// ---------------------------------------------------------------------------
// Kernel 0b: reorder branch conv weights -> wbr[br][o][kk*64+i] bf16
// ---------------------------------------------------------------------------
__global__ __launch_bounds__(256) void k0b_convw_branch(
    const float* __restrict__ conv_w, ushort* __restrict__ wbr)
{
    int e = blockIdx.x * 256 + threadIdx.x;     // 49152
    int i    = e & 63;
    int rest = e >> 6;
    int kk   = rest % 3;
    int orow = rest / 3;
    float v = conv_w[(size_t)orow * 192 + i * 3 + kk];
    wbr[(size_t)orow * 192 + kk * 64 + i] = f2b(v);
}

// ---------------------------------------------------------------------------
// Kernel 0c: transpose x [B][C][L] fp32 -> xT [B][L][C] bf16
// ---------------------------------------------------------------------------
__global__ __launch_bounds__(256) void k0c_xT(const float* __restrict__ x,
                                              ushort* __restrict__ xT)
{
    const int p0    = blockIdx.x * 64;
    const int batch = blockIdx.y;
    const int tid   = threadIdx.x;

    __shared__ uint ls[256 * 33];

    const float* xb = x + (size_t)batch * CCH * LSEQ;
#pragma unroll
    for (int pass = 0; pass < 16; ++pass) {
        int e  = tid + pass * 256;
        int ch = e >> 4;
        int c4 = e & 15;
        float4 v = *(const float4*)&xb[(size_t)ch * LSEQ + p0 + c4 * 4];
        uint u0 = (uint)f2b(v.x) | ((uint)f2b(v.y) << 16);
        uint u1 = (uint)f2b(v.z) | ((uint)f2b(v.w) << 16);
        ls[ch * 33 + c4 * 2]     = u0;
        ls[ch * 33 + c4 * 2 + 1] = u1;
    }
    __syncthreads();

    const int w = tid >> 6, l = tid & 63;
    const ushort* lsu = (const ushort*)ls;
    ushort* dst = xT + ((size_t)batch * LSEQ + p0) * CCH;
#pragma unroll
    for (int r = 0; r < 16; ++r) {
        int p = w * 16 + r;
#pragma unroll
        for (int q = 0; q < 4; ++q) {
            int ch = l + 64 * q;
            dst[(size_t)p * CCH + ch] = lsu[ch * 66 + p];
        }
    }
}

// ---------------------------------------------------------------------------
// Kernel 1: dilated conv(k=3) MFMA GEMM + BN + fast GELU, multi-tile.
// K1T=2, grid (16, 4 branches, 16 batch) -> 1024 blocks = 4/CU
// ---------------------------------------------------------------------------
#define SXA 72
#define SWB 200
#define K1T 2
__global__ __launch_bounds__(256) void k1_conv_mfma(
    const ushort* __restrict__ xT, const ushort* __restrict__ wbr,
    const float* __restrict__ conv_b, const float* __restrict__ bn_gamma,
    const float* __restrict__ bn_beta, const float* __restrict__ bn_mean,
    const float* __restrict__ bn_var, ushort* __restrict__ hT)
{
    const int br    = blockIdx.y;
    const int batch = blockIdx.z;
    const int d     = 1 << br;
    const int tid   = threadIdx.x;
    const int wm    = tid >> 6;
    const int lane  = tid & 63;
    const int lo    = lane & 15;
    const int hi    = lane >> 4;

    __shared__ ushort xsA[144 * SXA];   // A tile / reused as output transpose
    __shared__ ushort wlB[64 * SWB];

    const ushort* xTb = xT + (size_t)batch * LSEQ * CCH + br * CB;

    // ---- stage B once ----
    {
        const ushort* wrow = wbr + ((size_t)br * CB) * 192;
#pragma unroll
        for (int pass = 0; pass < 6; ++pass) {
            int e = tid + pass * 256;
            int o = e / 24;
            int c = e - o * 24;
            uint4 v = *(const uint4*)&wrow[e * 8];
            *(uint4*)&wlB[o * SWB + c * 8] = v;
        }
    }
    // ---- hoist BN params (loop-invariant) ----
    float bias[4], sc[4], sh[4];
#pragma unroll
    for (int ni = 0; ni < 4; ++ni) {
        const int go = br * CB + ni * 16 + lo;
        bias[ni] = conv_b[go];
        float inv = rsqrtf(bn_var[go] + BN_EPS);
        sc[ni] = bn_gamma[go] * inv;
        sh[ni] = bn_beta[go] - bn_mean[go] * sc[ni];
    }

    const int arow = tid >> 3;
    const int acol = tid & 7;
    uint4 areg[5];
    {
        const int t0 = blockIdx.x * (K1T * 128);
#pragma unroll
        for (int pass = 0; pass < 5; ++pass) {
            int p = arow + pass * 32;
            areg[pass] = make_uint4(0u, 0u, 0u, 0u);
            if (p < 144) {
                int gp = t0 - 8 + p;
                if (gp >= 0 && gp < LSEQ)
                    areg[pass] = *(const uint4*)&xTb[(size_t)gp * CCH + acol * 8];
            }
        }
    }

    for (int t = 0; t < K1T; ++t) {
        const int t0 = blockIdx.x * (K1T * 128) + t * 128;
        __syncthreads();
#pragma unroll
        for (int pass = 0; pass < 5; ++pass) {
            int p = arow + pass * 32;
            if (p < 144) *(uint4*)&xsA[p * SXA + acol * 8] = areg[pass];
        }
        __syncthreads();

        f32x4 acc[2][4];
#pragma unroll
        for (int mi = 0; mi < 2; ++mi)
#pragma unroll
            for (int ni = 0; ni < 4; ++ni) acc[mi][ni] = (f32x4)0.f;

#pragma unroll
        for (int kk = 0; kk < 3; ++kk) {
            const int roff = 8 + (kk - 1) * d;
#pragma unroll
            for (int ks = 0; ks < 2; ++ks) {
                bf16x8 af[2], bfr[4];
#pragma unroll
                for (int mi = 0; mi < 2; ++mi)
                    af[mi] = *(const bf16x8*)&xsA[
                        (wm * 32 + mi * 16 + lo + roff) * SXA + ks * 32 + hi * 8];
#pragma unroll
                for (int ni = 0; ni < 4; ++ni)
                    bfr[ni] = *(const bf16x8*)&wlB[
                        (ni * 16 + lo) * SWB + kk * 64 + ks * 32 + hi * 8];
#pragma unroll
                for (int mi = 0; mi < 2; ++mi)
#pragma unroll
                    for (int ni = 0; ni < 4; ++ni)
                        acc[mi][ni] = __builtin_amdgcn_mfma_f32_16x16x32_bf16(
                            af[mi], bfr[ni], acc[mi][ni], 0, 0, 0);
            }
        }

        // ---- issue next tile's A loads (latency hides under epilogue) ----
        if (t + 1 < K1T) {
            const int tn = t0 + 128;
#pragma unroll
            for (int pass = 0; pass < 5; ++pass) {
                int p = arow + pass * 32;
                areg[pass] = make_uint4(0u, 0u, 0u, 0u);
                if (p < 144) {
                    int gp = tn - 8 + p;
                    if (gp >= 0 && gp < LSEQ)
                        areg[pass] = *(const uint4*)&xTb[(size_t)gp * CCH + acol * 8];
                }
            }
        }

        __syncthreads();
        ushort* os = xsA;                // reuse as [128 pos][64 ch]
#pragma unroll
        for (int ni = 0; ni < 4; ++ni) {
            const int o = ni * 16 + lo;
#pragma unroll
            for (int mi = 0; mi < 2; ++mi) {
                const int prow = wm * 32 + mi * 16 + hi * 4;
#pragma unroll
                for (int q = 0; q < 4; ++q) {
                    float v = acc[mi][ni][q] + bias[ni];
                    v = v * sc[ni] + sh[ni];
                    os[(prow + q) * SXA + o] = f2b(gelu_fast(v));
                }
            }
        }
        __syncthreads();
        ushort* hTb = hT + ((size_t)batch * LSEQ + t0) * CCH + br * CB;
#pragma unroll
        for (int pass = 0; pass < 4; ++pass) {
            int e = tid + pass * 256;
            int r = e >> 3;
            int c = e & 7;
            *(uint4*)&hTb[(size_t)r * CCH + c * 8] = *(const uint4*)&xsA[r * SXA + c * 8];
        }
    }
}

// ---------------------------------------------------------------------------
// Kernel 2: streaming 25-tap edge-clamped moving average on hT -> hmaT
// ---------------------------------------------------------------------------
#define LS_S 68
__global__ __launch_bounds__(256) void k2_ma(
    const ushort* __restrict__ hT, ushort* __restrict__ hmaT)
{
    const int p0    = blockIdx.x * 128;
    const int cg    = blockIdx.y;
    const int batch = blockIdx.z;
    const int tid   = threadIdx.x;

    __shared__ ushort ls[152 * LS_S];
    __shared__ ushort os[128 * LS_S];

    const ushort* src = hT + ((size_t)batch * LSEQ) * CCH + cg * 64;
#pragma unroll
    for (int pass = 0; pass < 10; ++pass) {
        int e = tid + pass * 256;
        int r = e >> 4;
        int c = e & 15;
        if (r < 152) {
            int gp = p0 - MA_H + r;
            gp = max(0, min(LSEQ - 1, gp));
            *(uint2*)&ls[r * LS_S + c * 4] = *(const uint2*)&src[(size_t)gp * CCH + c * 4];
        }
    }
    __syncthreads();

    const int ch = tid & 63;
    const int pg = tid >> 6;
    const int r0 = pg * 32;
    const float inv25 = 1.f / 25.f;

    float s = 0.f;
#pragma unroll
    for (int t = 0; t < 25; ++t) s += b2f(ls[(r0 + t) * LS_S + ch]);
    os[(r0 + 0) * LS_S + ch] = f2b(s * inv25);
#pragma unroll
    for (int t = 1; t < 32; ++t) {
        s += b2f(ls[(r0 + 24 + t) * LS_S + ch]) - b2f(ls[(r0 + t - 1) * LS_S + ch]);
        os[(r0 + t) * LS_S + ch] = f2b(s * inv25);
    }
    __syncthreads();

    ushort* dst = hmaT + ((size_t)batch * LSEQ + p0) * CCH + cg * 64;
#pragma unroll
    for (int pass = 0; pass < 8; ++pass) {
        int e = tid + pass * 256;
        int r = e >> 4;
        int c = e & 15;
        *(uint2*)&dst[(size_t)r * CCH + c * 4] = *(const uint2*)&os[r * LS_S + c * 4];
    }
}

// ---------------------------------------------------------------------------
// Kernel 3: fusion GEMM (cumsum-folded weights) + bias + ReLU + alpha*x
// Round-16 T3+T4 pipeline (0 bank conflicts, no spill, 48us).  NEW: the
// epilogue reads x from xT (bf16, 32MB, L3-resident) via an LDS-staged
// [128 pos][128 ch] slice (stride 136: 16B-aligned, 2-way banks) instead
// of 64 MB of fp32 x from HBM.  k3 no longer touches x at all.
// ---------------------------------------------------------------------------
#define KTOT 512
__global__ __launch_bounds__(256) void k3_fusion(
    const ushort* __restrict__ hT, const ushort* __restrict__ hmaT,
    const ushort* __restrict__ wbf2, const float* __restrict__ fb,
    const ushort* __restrict__ xT, const float* __restrict__ alpha,
    float* __restrict__ out)
{
    const int t0    = blockIdx.x * 128;
    const int oBase = blockIdx.y * 128;
    const int batch = blockIdx.z;
    const int tid   = threadIdx.x;
    const int wid   = tid >> 6;
    const int lane  = tid & 63;
    const int lo    = lane & 15;
    const int hi    = lane >> 4;
    const int wm    = wid >> 1;
    const int wn    = wid & 1;

    // one block: A dbuf [2][8192] | W dbuf [2][8192]  (64 KiB total);
    // after the K-loop the whole area is dead -> x_l[128][136] (34 KB)
    __shared__ __align__(16) ushort SMEM3[32768];
    ushort* x_l = SMEM3;                 // [p][136] after main loop

    f32x4 acc[4][4];
#pragma unroll
    for (int mi = 0; mi < 4; ++mi)
#pragma unroll
        for (int ni = 0; ni < 4; ++ni) acc[mi][ni] = (f32x4)0.f;

    const ushort* hTb   = hT   + ((size_t)(batch * LSEQ + t0)) * CCH;
    const ushort* hmaTb = hmaT + ((size_t)(batch * LSEQ + t0)) * CCH;
    const ushort* wb    = wbf2 + (size_t)oBase * KTOT;

    const int srow0 = lane >> 3;
    const int scc   = lane & 7;

#define K3_STAGE2(buf, kn)                                                    \
    {                                                                         \
        const ushort* asrc = ((kn) < 256) ? (hTb + (kn))                      \
                                          : (hmaTb + ((kn) - 256));           \
        _Pragma("unroll")                                                     \
        for (int i = 0; i < 4; ++i) {                                         \
            int s = wid * 4 + i;                                              \
            int r = s * 8 + srow0;                                            \
            int q = scc ^ (r & 7);                                            \
            gload_lds16(asrc + (size_t)r * CCH + q * 8,                       \
                        (char*)(SMEM3 + (buf) * 8192) + s * 1024);            \
        }                                                                     \
        _Pragma("unroll")                                                     \
        for (int i = 0; i < 4; ++i) {                                         \
            int s = wid * 4 + i;                                              \
            int r = s * 8 + srow0;                                            \
            int q = scc ^ (r & 7);                                            \
            gload_lds16(wb + (size_t)r * KTOT + (kn) + q * 8,                 \
                        (char*)(SMEM3 + 16384 + (buf) * 8192) + s * 1024);    \
        }                                                                     \
    }

    K3_STAGE2(0, 0);

    int cur = 0;
    for (int k0 = 0; k0 < KTOT; k0 += 64) {
        if (k0 + 64 < KTOT) {
            K3_STAGE2(cur ^ 1, k0 + 64);             // async; stays in flight
            asm volatile("s_waitcnt vmcnt(8)" ::: "memory");  // stage(cur) done
        } else {
            asm volatile("s_waitcnt vmcnt(0)" ::: "memory");
        }
        __builtin_amdgcn_sched_barrier(0);
        __builtin_amdgcn_s_barrier();                // all waves' stage visible

#pragma unroll
        for (int ks = 0; ks < 2; ++ks) {
            bf16x8 af[4], bfr[4];
#pragma unroll
            for (int mi = 0; mi < 4; ++mi) {
                int row = wm * 64 + mi * 16 + lo;
                int cc = (ks * 4 + hi) ^ (row & 7);
                af[mi] = *(const bf16x8*)&SMEM3[cur * 8192 + row * 64 + cc * 8];
            }
#pragma unroll
            for (int ni = 0; ni < 4; ++ni) {
                int row = wn * 64 + ni * 16 + lo;
                int cc = (ks * 4 + hi) ^ (row & 7);
                bfr[ni] = *(const bf16x8*)&SMEM3[16384 + cur * 8192 + row * 64 + cc * 8];
            }
#pragma unroll
            for (int mi = 0; mi < 4; ++mi)
#pragma unroll
                for (int ni = 0; ni < 4; ++ni)
                    acc[mi][ni] = __builtin_amdgcn_mfma_f32_16x16x32_bf16(
                        af[mi], bfr[ni], acc[mi][ni], 0, 0, 0);
        }
        asm volatile("s_waitcnt lgkmcnt(0)" ::: "memory");
        __builtin_amdgcn_sched_barrier(0);
        __builtin_amdgcn_s_barrier();                // reads done before overwrite
        cur ^= 1;
    }

    // ---- stage xT slice [t0..t0+127][oBase..oBase+127] -> x_l (coalesced) --
    {
        const ushort* xs = xT + ((size_t)(batch * LSEQ + t0)) * CCH + oBase;
#pragma unroll
        for (int pass = 0; pass < 8; ++pass) {
            int e = tid + pass * 256;    // 128 rows x 16 chunks of 16B
            int r = e >> 4;
            int c = e & 15;
            uint4 v = *(const uint4*)&xs[(size_t)r * CCH + c * 8];
            *(uint4*)&x_l[r * 136 + c * 8] = v;
        }
    }
    __syncthreads();

    // ---- epilogue: ReLU(acc + bias) + alpha*x  (x from LDS, bf16) ----
    const float al = alpha[0];
#pragma unroll
    for (int ni = 0; ni < 4; ++ni) {
        const int ol = wn * 64 + ni * 16 + lo;
        const int o  = oBase + ol;
        const float bias = fb[o];
#pragma unroll
        for (int mi = 0; mi < 4; ++mi) {
            const int pl  = wm * 64 + mi * 16 + hi * 4;
            const int pos = t0 + pl;
            size_t base = ((size_t)(batch * CCH + o)) * LSEQ + pos;
            float4 ov;
            ov.x = fmaxf(acc[mi][ni][0] + bias, 0.f) + al * b2f(x_l[(pl + 0) * 136 + ol]);
            ov.y = fmaxf(acc[mi][ni][1] + bias, 0.f) + al * b2f(x_l[(pl + 1) * 136 + ol]);
            ov.z = fmaxf(acc[mi][ni][2] + bias, 0.f) + al * b2f(x_l[(pl + 2) * 136 + ol]);
            ov.w = fmaxf(acc[mi][ni][3] + bias, 0.f) + al * b2f(x_l[(pl + 3) * 136 + ol]);
            *(float4*)&out[base] = ov;
        }
    }
}

// ---------------------------------------------------------------------------
extern "C" void kernel_launch(void* const* d_in, const int* in_sizes, int n_in,
                              void* d_out, int out_size, void* d_ws, size_t ws_size,
                              hipStream_t stream)
{
    const float* x        = (const float*)d_in[0];
    const float* conv_w   = (const float*)d_in[1];
    const float* conv_b   = (const float*)d_in[2];
    const float* bn_gamma = (const float*)d_in[3];
    const float* bn_beta  = (const float*)d_in[4];
    const float* bn_mean  = (const float*)d_in[5];
    const float* bn_var   = (const float*)d_in[6];
    const float* fw       = (const float*)d_in[7];
    const float* fb       = (const float*)d_in[8];
    const float* alpha    = (const float*)d_in[9];
    float* out = (float*)d_out;

    ushort* hT    = (ushort*)d_ws;                                      // 32 MiB
    ushort* hmaT  = (ushort*)((char*)d_ws + (size_t)32 * 1024 * 1024);  // 32 MiB
    ushort* wbf2  = (ushort*)((char*)d_ws + (size_t)96 * 1024 * 1024);  // 256 KiB
    ushort* wbr   = (ushort*)((char*)d_ws + (size_t)97 * 1024 * 1024);  // 96 KiB
    ushort* xT    = (ushort*)((char*)d_ws + (size_t)98 * 1024 * 1024);  // 32 MiB

    k0w_fusionw<<<dim3(64), 256, 0, stream>>>(fw, wbf2);
    k0b_convw_branch<<<dim3(192), 256, 0, stream>>>(conv_w, wbr);
    k0c_xT<<<dim3(64, 16), 256, 0, stream>>>(x, xT);

    dim3 g1(16, NB, BATCH);
    k1_conv_mfma<<<g1, 256, 0, stream>>>(xT, wbr, conv_b, bn_gamma, bn_beta,
                                         bn_mean, bn_var, hT);
    dim3 g2(32, 4, BATCH);
    k2_ma<<<g2, 256, 0, stream>>>(hT, hmaT);

    dim3 g3(32, 2, BATCH);
    k3_fusion<<<g3, 256, 0, stream>>>(hT, hmaT, wbf2, fb, xT, alpha, out);
}